// Round 5
// baseline (149.371 us; speedup 1.0000x reference)
//
#include <hip/hip_runtime.h>
#include <hip/hip_bf16.h>

#define DEV __device__ __forceinline__

typedef __attribute__((ext_vector_type(8)))  __bf16    bf16x8;
typedef __attribute__((ext_vector_type(4)))  int       int4v;
typedef __attribute__((ext_vector_type(2)))  unsigned  uint2v;
typedef __attribute__((ext_vector_type(16))) float     vfloat16;

#if __has_builtin(__builtin_amdgcn_permlane32_swap)
#define HAVE_PLSWAP 1
#endif

// pack two fp32 -> one dword of two bf16, low half = first arg.
// Round-to-nearest (ties up) via +0x8000, then one v_perm_b32 byte-select.
DEV int pkbf(float a, float b) {
    unsigned ua = __builtin_bit_cast(unsigned, a) + 0x8000u;
    unsigned ub = __builtin_bit_cast(unsigned, b) + 0x8000u;
    return (int)__builtin_amdgcn_perm(ua, ub, 0x03020706u);
}

DEV bf16x8 i4_to_frag(int4v v) { return __builtin_bit_cast(bf16x8, v); }

DEV vfloat16 mfma32(bf16x8 a, bf16x8 b, vfloat16 c) {
    return __builtin_amdgcn_mfma_f32_32x32x16_bf16(a, b, c, 0, 0, 0);
}

// ---- C-layout 8-reg group -> B-frag (K=16), relu folded ----
// C layout: col=lane&31, row=(reg&3)+8*(reg>>2)+4*h   (h = lane>=32)
// B layout: n=lane&31,  k=(lane>>5)*8+j
DEV bf16x8 xposeB(float c0, float c1, float c2, float c3,
                  float c4, float c5, float c6, float c7, bool h) {
    int R0 = pkbf(fmaxf(c0, 0.f), fmaxf(c1, 0.f));   // rows (0,1)+4h
    int R1 = pkbf(fmaxf(c2, 0.f), fmaxf(c3, 0.f));   // rows (2,3)+4h
    int R2 = pkbf(fmaxf(c4, 0.f), fmaxf(c5, 0.f));   // rows (8,9)+4h
    int R3 = pkbf(fmaxf(c6, 0.f), fmaxf(c7, 0.f));   // rows (10,11)+4h
#ifdef HAVE_PLSWAP
    uint2v p0 = __builtin_amdgcn_permlane32_swap((unsigned)R0, (unsigned)R2, false, false);
    uint2v p1 = __builtin_amdgcn_permlane32_swap((unsigned)R1, (unsigned)R3, false, false);
    int4v v;
    v.x = (int)p0.x; v.y = (int)p1.x; v.z = (int)p0.y; v.w = (int)p1.y;
#else
    int S0 = h ? R0 : R2;
    int S1 = h ? R1 : R3;
    int Y0 = __shfl_xor(S0, 32, 64);
    int Y1 = __shfl_xor(S1, 32, 64);
    int4v v;
    v.x = h ? Y0 : R0;
    v.y = h ? Y1 : R1;
    v.z = h ? R2 : Y0;
    v.w = h ? R3 : Y1;
#endif
    return i4_to_frag(v);
}

// A-frag: A[m][k_global], m=lane&31, k_global = koff + 8*h + j.
// W row-major (K, ld): W[k][m].  Rows m>=Mact zero; k>=K zero.
// If bias != null, the k_global == K slot carries bias[m].
DEV bf16x8 make_afrag(const float* __restrict__ W, const float* __restrict__ bias,
                      int ld, int Mact, int K, int koff, int lane) {
    int m = lane & 31;
    int h = lane >> 5;
    int d[4];
#pragma unroll
    for (int i = 0; i < 4; ++i) {
        int k0 = koff + h * 8 + 2 * i;
        int k1 = k0 + 1;
        float w0 = 0.f, w1 = 0.f;
        if (m < Mact) {
            if (k0 < K) w0 = W[k0 * ld + m];
            else if (bias && k0 == K) w0 = bias[m];
            if (k1 < K) w1 = W[k1 * ld + m];
            else if (bias && k1 == K) w1 = bias[m];
        }
        d[i] = pkbf(w0, w1);
    }
    int4v v; v.x = d[0]; v.y = d[1]; v.z = d[2]; v.w = d[3];
    return i4_to_frag(v);
}

// bias vector in C layout (all 32 rows)
DEV vfloat16 bvec32(const float* __restrict__ b, int lane) {
    int h = lane >> 5;
    vfloat16 v;
#pragma unroll
    for (int reg = 0; reg < 16; ++reg)
        v[reg] = b[(reg & 3) + 8 * (reg >> 2) + 4 * h];
    return v;
}
// bias vector, rows 0..15 only (regs 0..7), upper 8 zero
DEV vfloat16 bvec16(const float* __restrict__ b, int lane) {
    int h = lane >> 5;
    vfloat16 v;
#pragma unroll
    for (int reg = 0; reg < 16; ++reg)
        v[reg] = (reg < 8) ? b[(reg & 3) + 8 * (reg >> 2) + 4 * h] : 0.f;
    return v;
}

DEV vfloat16 zero16() {
    vfloat16 z;
#pragma unroll
    for (int i = 0; i < 16; ++i) z[i] = 0.f;
    return z;
}

// B-frag for layer1: x at k=0..3, 1.0 at k=4 (bias slot).  Identical code for
// h-lanes: their elements map to k=8..15 where A1 is zero, so no masking.
DEV bf16x8 make_b1(float4 xa) {
    int4v v;
    v.x = pkbf(xa.x, xa.y);
    v.y = pkbf(xa.z, xa.w);
    v.z = 0x00003f80;          // bf16(1.0) at k=4
    v.w = 0;
    return i4_to_frag(v);
}

struct Frags {
    bf16x8 A1, A2lo, A2hi, A3lo, A3hi;
    vfloat16 b2, b3;   // L2/L3 biases as MFMA C-operand inits (L1 bias rides k=4)
};

DEV void load_frags(Frags& F,
                    const float* __restrict__ W1, const float* __restrict__ b1,
                    const float* __restrict__ W2, const float* __restrict__ b2,
                    const float* __restrict__ W3, const float* __restrict__ b3,
                    int lane) {
    F.A1   = make_afrag(W1, b1,      32, 32, 4,  0,  lane);
    F.A2lo = make_afrag(W2, nullptr, 32, 32, 32, 0,  lane);
    F.A2hi = make_afrag(W2, nullptr, 32, 32, 32, 16, lane);
    F.A3lo = make_afrag(W3, nullptr, 16, 16, 32, 0,  lane);
    F.A3hi = make_afrag(W3, nullptr, 16, 16, 32, 16, lane);
    F.b2 = bvec32(b2, lane);
    F.b3 = bvec16(b3, lane);
}

// finish chain from C1: L2 + L3, returns pre-relu C3 (regs 0..7 valid)
DEV vfloat16 finish_mlp(vfloat16 C1, const Frags& F, bool h) {
    bf16x8 Blo = xposeB(C1[0], C1[1], C1[2], C1[3], C1[4], C1[5], C1[6], C1[7], h);
    bf16x8 Bhi = xposeB(C1[8], C1[9], C1[10], C1[11], C1[12], C1[13], C1[14], C1[15], h);
    vfloat16 C2 = mfma32(F.A2lo, Blo, F.b2);
    C2 = mfma32(F.A2hi, Bhi, C2);
    Blo = xposeB(C2[0], C2[1], C2[2], C2[3], C2[4], C2[5], C2[6], C2[7], h);
    Bhi = xposeB(C2[8], C2[9], C2[10], C2[11], C2[12], C2[13], C2[14], C2[15], h);
    vfloat16 C3 = mfma32(F.A3lo, Blo, F.b3);
    C3 = mfma32(F.A3hi, Bhi, C3);
    return C3;
}

// LDS x-stage: [agent][row] float4, agent stride 132 dwords (128 + 4 pad)
#define XSTRIDE 132

// LDS weight-stage offsets (floats)
#define OFF_SW1 0
#define OFF_SB1 128
#define OFF_SW2 160
#define OFF_SB2 1184
#define OFF_SW3 1216
#define OFF_SB3 1728
#define OFF_GW1 1744
#define OFF_GB1 2768
#define OFF_GW2 2800
#define OFF_GB2 2864
#define WTOT    2866

DEV void cpw(float* __restrict__ dst, const float* __restrict__ src, int n, int tid) {
    for (int i = tid; i < n; i += 256) dst[i] = src[i];
}

__global__ __launch_bounds__(256)
void dqn_kernel(const float* __restrict__ x, const int* __restrict__ selp,
                const float* __restrict__ oW1, const float* __restrict__ ob1,
                const float* __restrict__ oW2, const float* __restrict__ ob2,
                const float* __restrict__ oW3, const float* __restrict__ ob3,
                const float* __restrict__ sW1, const float* __restrict__ sb1,
                const float* __restrict__ sW2, const float* __restrict__ sb2,
                const float* __restrict__ sW3, const float* __restrict__ sb3,
                const float* __restrict__ gW1, const float* __restrict__ gb1,
                const float* __restrict__ gW2, const float* __restrict__ gb2,
                float* __restrict__ out)
{
    __shared__ float lds_x[32 * XSTRIDE];     // 16.9 KB staged x
    __shared__ float lds_red[3][8][64];       // 6 KB partial agent-sums
    __shared__ float lds_w[WTOT];             // 11.5 KB epilogue weights

    const int tid  = threadIdx.x;
    const int lane = tid & 63;
    const int wave = tid >> 6;
    const bool h = lane >= 32;
    const int c = lane & 31;
    const int sel = *selp;
    const int base0 = blockIdx.x * 32;        // 32 batch rows per block

    // ---- stage x (coalesced) + epilogue weights into LDS ----
    {
        const float* xblk = x + (size_t)base0 * 128;
#pragma unroll
        for (int k = 0; k < 4; ++k) {
            int f = tid + 256 * k;
            int row = f >> 5;
            int ag  = f & 31;
            float4 v = *(const float4*)(xblk + (size_t)f * 4);
            *(float4*)&lds_x[ag * XSTRIDE + row * 4] = v;
        }
        cpw(lds_w + OFF_SW1, sW1, 128,  tid);
        cpw(lds_w + OFF_SB1, sb1, 32,   tid);
        cpw(lds_w + OFF_SW2, sW2, 1024, tid);
        cpw(lds_w + OFF_SB2, sb2, 32,   tid);
        cpw(lds_w + OFF_SW3, sW3, 512,  tid);
        cpw(lds_w + OFF_SB3, sb3, 16,   tid);
        cpw(lds_w + OFF_GW1, gW1, 1024, tid);
        cpw(lds_w + OFF_GB1, gb1, 32,   tid);
        cpw(lds_w + OFF_GW2, gW2, 64,   tid);
        cpw(lds_w + OFF_GB2, gb2, 2,    tid);
    }

    // "other"-MLP weight fragments (global; latency overlaps staging)
    Frags Fo;
    load_frags(Fo, oW1, ob1, oW2, ob2, oW3, ob3, lane);

    __syncthreads();

    // ---- main loop: 8 agents per wave, 2-stage software pipeline ----
    float sum[8] = {0.f, 0.f, 0.f, 0.f, 0.f, 0.f, 0.f, 0.f};
    const int a0 = wave * 8;
    const float* xbase = &lds_x[a0 * XSTRIDE + c * 4];

    // prologue: start chain 0
    vfloat16 C1 = mfma32(Fo.A1, make_b1(*(const float4*)xbase), zero16());
#pragma unroll
    for (int i = 0; i < 8; ++i) {
        vfloat16 C1n;
        if (i < 7) {   // start chain i+1 (independent of chain i's tail)
            float4 xn = *(const float4*)(xbase + (i + 1) * XSTRIDE);
            C1n = mfma32(Fo.A1, make_b1(xn), zero16());
        }
        vfloat16 C3 = finish_mlp(C1, Fo, h);
        if (a0 + i != sel) {
#pragma unroll
            for (int j = 0; j < 8; ++j) sum[j] += fmaxf(C3[j], 0.f);
        }
        if (i < 7) C1 = C1n;
    }

    // ---- merge partial sums across the 4 waves ----
    if (wave != 0) {
#pragma unroll
        for (int i = 0; i < 8; ++i) lds_red[wave - 1][i][lane] = sum[i];
    }
    __syncthreads();

    if (wave == 0) {
#pragma unroll
        for (int j = 0; j < 3; ++j)
#pragma unroll
            for (int i = 0; i < 8; ++i) sum[i] += lds_red[j][i][lane];

        // selected-agent MLP — weights from LDS stage
        Frags Fs;
        load_frags(Fs, lds_w + OFF_SW1, lds_w + OFF_SB1,
                       lds_w + OFF_SW2, lds_w + OFF_SB2,
                       lds_w + OFF_SW3, lds_w + OFF_SB3, lane);
        float4 xs = *(const float4*)&lds_x[sel * XSTRIDE + c * 4];
        vfloat16 C1s = mfma32(Fs.A1, make_b1(xs), zero16());
        vfloat16 C3s = finish_mlp(C1s, Fs, h);

        // gate layer 1: concat([sel_out, sum_other]) @ gW1 + gb1, relu
        bf16x8 Ag_lo = make_afrag(lds_w + OFF_GW1, nullptr, 32, 32, 32, 0,  lane);
        bf16x8 Ag_hi = make_afrag(lds_w + OFF_GW1, nullptr, 32, 32, 32, 16, lane);
        vfloat16 gb1v = bvec32(lds_w + OFF_GB1, lane);
        bf16x8 Bg_lo = xposeB(C3s[0], C3s[1], C3s[2], C3s[3],
                              C3s[4], C3s[5], C3s[6], C3s[7], h);   // relu folded
        bf16x8 Bg_hi = xposeB(sum[0], sum[1], sum[2], sum[3],
                              sum[4], sum[5], sum[6], sum[7], h);   // sums >= 0
        vfloat16 G = mfma32(Ag_lo, Bg_lo, gb1v);
        G = mfma32(Ag_hi, Bg_hi, G);
#pragma unroll
        for (int i = 0; i < 16; ++i) G[i] = fmaxf(G[i], 0.f);

        // gate layer 2 (32 -> 2) in fp32 VALU + cross-half reduce
        const float* gw2l = lds_w + OFF_GW2;
        float q0 = 0.f, q1 = 0.f;
#pragma unroll
        for (int reg = 0; reg < 16; ++reg) {
            int row = (reg & 3) + 8 * (reg >> 2) + (h ? 4 : 0);
            q0 += G[reg] * gw2l[row * 2 + 0];
            q1 += G[reg] * gw2l[row * 2 + 1];
        }
        q0 += __shfl_xor(q0, 32, 64);
        q1 += __shfl_xor(q1, 32, 64);
        q0 += lds_w[OFF_GB2 + 0];
        q1 += lds_w[OFF_GB2 + 1];

        if (!h) {
            int act = (int)xs.w;            // action index from feature 3
            act = act < 0 ? 0 : (act > 1 ? 1 : act);
            out[base0 + c] = act ? q1 : q0;
        }
    }
}

extern "C" void kernel_launch(void* const* d_in, const int* in_sizes, int n_in,
                              void* d_out, int out_size, void* d_ws, size_t ws_size,
                              hipStream_t stream) {
    const float* x   = (const float*)d_in[0];
    const int*   sel = (const int*)d_in[1];
    const float* oW1 = (const float*)d_in[2];
    const float* ob1 = (const float*)d_in[3];
    const float* oW2 = (const float*)d_in[4];
    const float* ob2 = (const float*)d_in[5];
    const float* oW3 = (const float*)d_in[6];
    const float* ob3 = (const float*)d_in[7];
    const float* sW1 = (const float*)d_in[8];
    const float* sb1 = (const float*)d_in[9];
    const float* sW2 = (const float*)d_in[10];
    const float* sb2 = (const float*)d_in[11];
    const float* sW3 = (const float*)d_in[12];
    const float* sb3 = (const float*)d_in[13];
    const float* gW1 = (const float*)d_in[14];
    const float* gb1 = (const float*)d_in[15];
    const float* gW2 = (const float*)d_in[16];
    const float* gb2 = (const float*)d_in[17];
    float* out = (float*)d_out;

    const int B = in_sizes[0] / 128;       // 65536
    const int blocks = B / 32;             // 32 batch rows per block, 8 agents/wave
    dqn_kernel<<<blocks, 256, 0, stream>>>(x, sel,
                                           oW1, ob1, oW2, ob2, oW3, ob3,
                                           sW1, sb1, sW2, sb2, sW3, sb3,
                                           gW1, gb1, gW2, gb2, out);
}

// Round 6
// 135.151 us; speedup vs baseline: 1.1052x; 1.1052x over previous
//
#include <hip/hip_runtime.h>
#include <hip/hip_bf16.h>

#define DEV __device__ __forceinline__

typedef __attribute__((ext_vector_type(8)))  __bf16    bf16x8;
typedef __attribute__((ext_vector_type(4)))  int       int4v;
typedef __attribute__((ext_vector_type(2)))  unsigned  uint2v;
typedef __attribute__((ext_vector_type(16))) float     vfloat16;

#if __has_builtin(__builtin_amdgcn_permlane32_swap)
#define HAVE_PLSWAP 1
#endif

// pack two fp32 -> one dword of two bf16, low half = first arg.
// Round-to-nearest (ties up) via +0x8000, then one v_perm_b32 byte-select.
DEV int pkbf(float a, float b) {
    unsigned ua = __builtin_bit_cast(unsigned, a) + 0x8000u;
    unsigned ub = __builtin_bit_cast(unsigned, b) + 0x8000u;
    return (int)__builtin_amdgcn_perm(ua, ub, 0x03020706u);
}

DEV bf16x8 i4_to_frag(int4v v) { return __builtin_bit_cast(bf16x8, v); }

DEV vfloat16 mfma32(bf16x8 a, bf16x8 b, vfloat16 c) {
    return __builtin_amdgcn_mfma_f32_32x32x16_bf16(a, b, c, 0, 0, 0);
}

// ---- C-layout 8-reg group -> B-frag (K=16), relu folded ----
// C layout: col=lane&31, row=(reg&3)+8*(reg>>2)+4*h   (h = lane>=32)
// B layout: n=lane&31,  k=(lane>>5)*8+j
DEV bf16x8 xposeB(float c0, float c1, float c2, float c3,
                  float c4, float c5, float c6, float c7, bool h) {
    int R0 = pkbf(fmaxf(c0, 0.f), fmaxf(c1, 0.f));   // rows (0,1)+4h
    int R1 = pkbf(fmaxf(c2, 0.f), fmaxf(c3, 0.f));   // rows (2,3)+4h
    int R2 = pkbf(fmaxf(c4, 0.f), fmaxf(c5, 0.f));   // rows (8,9)+4h
    int R3 = pkbf(fmaxf(c6, 0.f), fmaxf(c7, 0.f));   // rows (10,11)+4h
#ifdef HAVE_PLSWAP
    uint2v p0 = __builtin_amdgcn_permlane32_swap((unsigned)R0, (unsigned)R2, false, false);
    uint2v p1 = __builtin_amdgcn_permlane32_swap((unsigned)R1, (unsigned)R3, false, false);
    int4v v;
    v.x = (int)p0.x; v.y = (int)p1.x; v.z = (int)p0.y; v.w = (int)p1.y;
#else
    int S0 = h ? R0 : R2;
    int S1 = h ? R1 : R3;
    int Y0 = __shfl_xor(S0, 32, 64);
    int Y1 = __shfl_xor(S1, 32, 64);
    int4v v;
    v.x = h ? Y0 : R0;
    v.y = h ? Y1 : R1;
    v.z = h ? R2 : Y0;
    v.w = h ? R3 : Y1;
#endif
    return i4_to_frag(v);
}

// A-frag: A[m][k_global], m=lane&31, k_global = koff + 8*h + j.
// W row-major (K, ld): W[k][m].  Rows m>=Mact zero; k>=K zero.
// If bias != null, the k_global == K slot carries bias[m].
DEV bf16x8 make_afrag(const float* __restrict__ W, const float* __restrict__ bias,
                      int ld, int Mact, int K, int koff, int lane) {
    int m = lane & 31;
    int h = lane >> 5;
    int d[4];
#pragma unroll
    for (int i = 0; i < 4; ++i) {
        int k0 = koff + h * 8 + 2 * i;
        int k1 = k0 + 1;
        float w0 = 0.f, w1 = 0.f;
        if (m < Mact) {
            if (k0 < K) w0 = W[k0 * ld + m];
            else if (bias && k0 == K) w0 = bias[m];
            if (k1 < K) w1 = W[k1 * ld + m];
            else if (bias && k1 == K) w1 = bias[m];
        }
        d[i] = pkbf(w0, w1);
    }
    int4v v; v.x = d[0]; v.y = d[1]; v.z = d[2]; v.w = d[3];
    return i4_to_frag(v);
}

// bias vector in C layout (all 32 rows)
DEV vfloat16 bvec32(const float* __restrict__ b, int lane) {
    int h = lane >> 5;
    vfloat16 v;
#pragma unroll
    for (int reg = 0; reg < 16; ++reg)
        v[reg] = b[(reg & 3) + 8 * (reg >> 2) + 4 * h];
    return v;
}
// bias vector, rows 0..15 only (regs 0..7), upper 8 zero
DEV vfloat16 bvec16(const float* __restrict__ b, int lane) {
    int h = lane >> 5;
    vfloat16 v;
#pragma unroll
    for (int reg = 0; reg < 16; ++reg)
        v[reg] = (reg < 8) ? b[(reg & 3) + 8 * (reg >> 2) + 4 * h] : 0.f;
    return v;
}

DEV vfloat16 zero16() {
    vfloat16 z;
#pragma unroll
    for (int i = 0; i < 16; ++i) z[i] = 0.f;
    return z;
}

// B1 frag from pre-packed LDS dwords: x at k=0..3, 1.0 at k=4 (bias slot).
// h-lanes map to k=8..15 where A1 is zero -> no masking needed.
DEV bf16x8 b1_from(int2 d) {
    int4v v;
    v.x = d.x;
    v.y = d.y;
    v.z = 0x00003f80;          // bf16(1.0) at k=4
    v.w = 0;
    return i4_to_frag(v);
}

struct Frags {
    bf16x8 A1, A2lo, A2hi, A3lo, A3hi;
    vfloat16 b2, b3;   // L2/L3 biases as MFMA C-operand inits (L1 bias rides k=4)
};

DEV void load_frags(Frags& F,
                    const float* __restrict__ W1, const float* __restrict__ b1,
                    const float* __restrict__ W2, const float* __restrict__ b2,
                    const float* __restrict__ W3, const float* __restrict__ b3,
                    int lane) {
    F.A1   = make_afrag(W1, b1,      32, 32, 4,  0,  lane);
    F.A2lo = make_afrag(W2, nullptr, 32, 32, 32, 0,  lane);
    F.A2hi = make_afrag(W2, nullptr, 32, 32, 32, 16, lane);
    F.A3lo = make_afrag(W3, nullptr, 16, 16, 32, 0,  lane);
    F.A3hi = make_afrag(W3, nullptr, 16, 16, 32, 16, lane);
    F.b2 = bvec32(b2, lane);
    F.b3 = bvec16(b3, lane);
}

// single chain (epilogue use): L1..L3, returns pre-relu C3 (regs 0..7 valid)
DEV vfloat16 run_mlp3(bf16x8 B1, const Frags& F, bool h) {
    vfloat16 C1 = mfma32(F.A1, B1, zero16());
    bf16x8 Blo = xposeB(C1[0], C1[1], C1[2], C1[3], C1[4], C1[5], C1[6], C1[7], h);
    bf16x8 Bhi = xposeB(C1[8], C1[9], C1[10], C1[11], C1[12], C1[13], C1[14], C1[15], h);
    vfloat16 C2 = mfma32(F.A2lo, Blo, F.b2);
    C2 = mfma32(F.A2hi, Bhi, C2);
    Blo = xposeB(C2[0], C2[1], C2[2], C2[3], C2[4], C2[5], C2[6], C2[7], h);
    Bhi = xposeB(C2[8], C2[9], C2[10], C2[11], C2[12], C2[13], C2[14], C2[15], h);
    vfloat16 C3 = mfma32(F.A3lo, Blo, F.b3);
    C3 = mfma32(F.A3hi, Bhi, C3);
    return C3;
}

// LDS x-stage: pre-packed bf16, [agent][row] int2, agent stride 66 dwords
// (64 + 2 pad -> staging writes land on stepped banks, 2-way max)
#define XSTRIDE 66

__global__ __launch_bounds__(256)
void dqn_kernel(const float* __restrict__ x, const int* __restrict__ selp,
                const float* __restrict__ oW1, const float* __restrict__ ob1,
                const float* __restrict__ oW2, const float* __restrict__ ob2,
                const float* __restrict__ oW3, const float* __restrict__ ob3,
                const float* __restrict__ sW1, const float* __restrict__ sb1,
                const float* __restrict__ sW2, const float* __restrict__ sb2,
                const float* __restrict__ sW3, const float* __restrict__ sb3,
                const float* __restrict__ gW1, const float* __restrict__ gb1,
                const float* __restrict__ gW2, const float* __restrict__ gb2,
                float* __restrict__ out)
{
    __shared__ int   lds_xb[32 * XSTRIDE];    // 8.4 KB pre-packed bf16 x
    __shared__ float lds_red[3][8][64];       // 6 KB partial agent-sums

    const int tid  = threadIdx.x;
    const int lane = tid & 63;
    const int wave = tid >> 6;
    const bool h = lane >= 32;
    const int c = lane & 31;
    const int sel = *selp;
    const int base0 = blockIdx.x * 32;        // 32 batch rows per block

    // ---- stage x: coalesced fp32 read -> bf16 pack -> LDS [agent][row] ----
    {
        const float* xblk = x + (size_t)base0 * 128;
#pragma unroll
        for (int k = 0; k < 4; ++k) {
            int f = tid + 256 * k;            // float4 index in 32x32 tile
            int row = f >> 5;
            int ag  = f & 31;
            float4 v = *(const float4*)(xblk + (size_t)f * 4);
            int2 d;
            d.x = pkbf(v.x, v.y);
            d.y = pkbf(v.z, v.w);
            *(int2*)&lds_xb[ag * XSTRIDE + row * 2] = d;
        }
    }

    // "other"-MLP weight fragments (global; latency overlaps staging)
    Frags Fo;
    load_frags(Fo, oW1, ob1, oW2, ob2, oW3, ob3, lane);

    __syncthreads();

    // ---- main loop: 8 agents per wave, TWO chains fully interleaved ----
    float sum[8] = {0.f, 0.f, 0.f, 0.f, 0.f, 0.f, 0.f, 0.f};
    const int a0 = wave * 8;
    const int* xb = &lds_xb[a0 * XSTRIDE + c * 2];

#pragma unroll
    for (int i = 0; i < 8; i += 2) {
        int2 da = *(const int2*)(xb + i * XSTRIDE);
        int2 db = *(const int2*)(xb + (i + 1) * XSTRIDE);

        vfloat16 C1a = mfma32(Fo.A1, b1_from(da), zero16());
        vfloat16 C1b = mfma32(Fo.A1, b1_from(db), zero16());

        bf16x8 Bal = xposeB(C1a[0], C1a[1], C1a[2], C1a[3], C1a[4], C1a[5], C1a[6], C1a[7], h);
        bf16x8 Bbl = xposeB(C1b[0], C1b[1], C1b[2], C1b[3], C1b[4], C1b[5], C1b[6], C1b[7], h);
        bf16x8 Bah = xposeB(C1a[8], C1a[9], C1a[10], C1a[11], C1a[12], C1a[13], C1a[14], C1a[15], h);
        bf16x8 Bbh = xposeB(C1b[8], C1b[9], C1b[10], C1b[11], C1b[12], C1b[13], C1b[14], C1b[15], h);

        vfloat16 C2a = mfma32(Fo.A2lo, Bal, Fo.b2);
        vfloat16 C2b = mfma32(Fo.A2lo, Bbl, Fo.b2);
        C2a = mfma32(Fo.A2hi, Bah, C2a);
        C2b = mfma32(Fo.A2hi, Bbh, C2b);

        Bal = xposeB(C2a[0], C2a[1], C2a[2], C2a[3], C2a[4], C2a[5], C2a[6], C2a[7], h);
        Bbl = xposeB(C2b[0], C2b[1], C2b[2], C2b[3], C2b[4], C2b[5], C2b[6], C2b[7], h);
        Bah = xposeB(C2a[8], C2a[9], C2a[10], C2a[11], C2a[12], C2a[13], C2a[14], C2a[15], h);
        Bbh = xposeB(C2b[8], C2b[9], C2b[10], C2b[11], C2b[12], C2b[13], C2b[14], C2b[15], h);

        vfloat16 C3a = mfma32(Fo.A3lo, Bal, Fo.b3);
        vfloat16 C3b = mfma32(Fo.A3lo, Bbl, Fo.b3);
        C3a = mfma32(Fo.A3hi, Bah, C3a);
        C3b = mfma32(Fo.A3hi, Bbh, C3b);

        if (a0 + i != sel) {
#pragma unroll
            for (int j = 0; j < 8; ++j) sum[j] += fmaxf(C3a[j], 0.f);
        }
        if (a0 + i + 1 != sel) {
#pragma unroll
            for (int j = 0; j < 8; ++j) sum[j] += fmaxf(C3b[j], 0.f);
        }
    }

    // ---- merge partial sums across the 4 waves ----
    if (wave != 0) {
#pragma unroll
        for (int i = 0; i < 8; ++i) lds_red[wave - 1][i][lane] = sum[i];
    }
    __syncthreads();

    if (wave == 0) {
#pragma unroll
        for (int j = 0; j < 3; ++j)
#pragma unroll
            for (int i = 0; i < 8; ++i) sum[i] += lds_red[j][i][lane];

        // selected-agent MLP (packed x from LDS; weights from global/L2)
        Frags Fs;
        load_frags(Fs, sW1, sb1, sW2, sb2, sW3, sb3, lane);
        int2 ds = *(const int2*)&lds_xb[sel * XSTRIDE + c * 2];
        vfloat16 C3s = run_mlp3(b1_from(ds), Fs, h);

        // gate layer 1: concat([sel_out, sum_other]) @ gW1 + gb1, relu
        bf16x8 Ag_lo = make_afrag(gW1, nullptr, 32, 32, 32, 0,  lane);
        bf16x8 Ag_hi = make_afrag(gW1, nullptr, 32, 32, 32, 16, lane);
        vfloat16 gb1v = bvec32(gb1, lane);
        bf16x8 Bg_lo = xposeB(C3s[0], C3s[1], C3s[2], C3s[3],
                              C3s[4], C3s[5], C3s[6], C3s[7], h);   // relu folded
        bf16x8 Bg_hi = xposeB(sum[0], sum[1], sum[2], sum[3],
                              sum[4], sum[5], sum[6], sum[7], h);   // sums >= 0
        vfloat16 G = mfma32(Ag_lo, Bg_lo, gb1v);
        G = mfma32(Ag_hi, Bg_hi, G);
#pragma unroll
        for (int i = 0; i < 16; ++i) G[i] = fmaxf(G[i], 0.f);

        // gate layer 2 (32 -> 2) in fp32 VALU + cross-half reduce
        float q0 = 0.f, q1 = 0.f;
#pragma unroll
        for (int reg = 0; reg < 16; ++reg) {
            int row = (reg & 3) + 8 * (reg >> 2) + (h ? 4 : 0);
            q0 += G[reg] * gW2[row * 2 + 0];
            q1 += G[reg] * gW2[row * 2 + 1];
        }
        q0 += __shfl_xor(q0, 32, 64);
        q1 += __shfl_xor(q1, 32, 64);
        q0 += gb2[0];
        q1 += gb2[1];

        if (!h) {
            // action index MUST come from fp32 x (bf16 rounding of values
            // near 1.0 would flip the (int) cast)
            float f3 = x[(size_t)(base0 + c) * 128 + sel * 4 + 3];
            int act = (int)f3;
            act = act < 0 ? 0 : (act > 1 ? 1 : act);
            out[base0 + c] = act ? q1 : q0;
        }
    }
}

extern "C" void kernel_launch(void* const* d_in, const int* in_sizes, int n_in,
                              void* d_out, int out_size, void* d_ws, size_t ws_size,
                              hipStream_t stream) {
    const float* x   = (const float*)d_in[0];
    const int*   sel = (const int*)d_in[1];
    const float* oW1 = (const float*)d_in[2];
    const float* ob1 = (const float*)d_in[3];
    const float* oW2 = (const float*)d_in[4];
    const float* ob2 = (const float*)d_in[5];
    const float* oW3 = (const float*)d_in[6];
    const float* ob3 = (const float*)d_in[7];
    const float* sW1 = (const float*)d_in[8];
    const float* sb1 = (const float*)d_in[9];
    const float* sW2 = (const float*)d_in[10];
    const float* sb2 = (const float*)d_in[11];
    const float* sW3 = (const float*)d_in[12];
    const float* sb3 = (const float*)d_in[13];
    const float* gW1 = (const float*)d_in[14];
    const float* gb1 = (const float*)d_in[15];
    const float* gW2 = (const float*)d_in[16];
    const float* gb2 = (const float*)d_in[17];
    float* out = (float*)d_out;

    const int B = in_sizes[0] / 128;       // 65536
    const int blocks = B / 32;             // 32 batch rows per block, 8 agents/wave
    dqn_kernel<<<blocks, 256, 0, stream>>>(x, sel,
                                           oW1, ob1, oW2, ob2, oW3, ob3,
                                           sW1, sb1, sW2, sb2, sW3, sb3,
                                           gW1, gb1, gW2, gb2, out);
}

// Round 7
// 133.450 us; speedup vs baseline: 1.1193x; 1.0127x over previous
//
#include <hip/hip_runtime.h>
#include <hip/hip_bf16.h>

#define DEV __device__ __forceinline__

typedef __attribute__((ext_vector_type(8)))  __bf16    bf16x8;
typedef __attribute__((ext_vector_type(4)))  int       int4v;
typedef __attribute__((ext_vector_type(2)))  unsigned  uint2v;
typedef __attribute__((ext_vector_type(16))) float     vfloat16;

#if __has_builtin(__builtin_amdgcn_permlane32_swap)
#define HAVE_PLSWAP 1
#endif

// pack two fp32 -> one dword of two bf16, low half = first arg.
// Round-to-nearest (ties up) via +0x8000, then one v_perm_b32 byte-select.
DEV int pkbf(float a, float b) {
    unsigned ua = __builtin_bit_cast(unsigned, a) + 0x8000u;
    unsigned ub = __builtin_bit_cast(unsigned, b) + 0x8000u;
    return (int)__builtin_amdgcn_perm(ua, ub, 0x03020706u);
}

DEV bf16x8 i4_to_frag(int4v v) { return __builtin_bit_cast(bf16x8, v); }

DEV vfloat16 mfma32(bf16x8 a, bf16x8 b, vfloat16 c) {
    return __builtin_amdgcn_mfma_f32_32x32x16_bf16(a, b, c, 0, 0, 0);
}

// ---- C-layout 8-reg group -> B-frag (K=16), relu folded ----
// C layout: col=lane&31, row=(reg&3)+8*(reg>>2)+4*h   (h = lane>=32)
// B layout: n=lane&31,  k=(lane>>5)*8+j
DEV bf16x8 xposeB(float c0, float c1, float c2, float c3,
                  float c4, float c5, float c6, float c7, bool h) {
    int R0 = pkbf(fmaxf(c0, 0.f), fmaxf(c1, 0.f));   // rows (0,1)+4h
    int R1 = pkbf(fmaxf(c2, 0.f), fmaxf(c3, 0.f));   // rows (2,3)+4h
    int R2 = pkbf(fmaxf(c4, 0.f), fmaxf(c5, 0.f));   // rows (8,9)+4h
    int R3 = pkbf(fmaxf(c6, 0.f), fmaxf(c7, 0.f));   // rows (10,11)+4h
#ifdef HAVE_PLSWAP
    uint2v p0 = __builtin_amdgcn_permlane32_swap((unsigned)R0, (unsigned)R2, false, false);
    uint2v p1 = __builtin_amdgcn_permlane32_swap((unsigned)R1, (unsigned)R3, false, false);
    int4v v;
    v.x = (int)p0.x; v.y = (int)p1.x; v.z = (int)p0.y; v.w = (int)p1.y;
#else
    int S0 = h ? R0 : R2;
    int S1 = h ? R1 : R3;
    int Y0 = __shfl_xor(S0, 32, 64);
    int Y1 = __shfl_xor(S1, 32, 64);
    int4v v;
    v.x = h ? Y0 : R0;
    v.y = h ? Y1 : R1;
    v.z = h ? R2 : Y0;
    v.w = h ? R3 : Y1;
#endif
    return i4_to_frag(v);
}

// A-frag: A[m][k_global], m=lane&31, k_global = koff + 8*h + j.
// W row-major (K, ld): W[k][m].  Rows m>=Mact zero; k>=K zero.
// If bias != null, the k_global == K slot carries bias[m].
DEV bf16x8 make_afrag(const float* __restrict__ W, const float* __restrict__ bias,
                      int ld, int Mact, int K, int koff, int lane) {
    int m = lane & 31;
    int h = lane >> 5;
    int d[4];
#pragma unroll
    for (int i = 0; i < 4; ++i) {
        int k0 = koff + h * 8 + 2 * i;
        int k1 = k0 + 1;
        float w0 = 0.f, w1 = 0.f;
        if (m < Mact) {
            if (k0 < K) w0 = W[k0 * ld + m];
            else if (bias && k0 == K) w0 = bias[m];
            if (k1 < K) w1 = W[k1 * ld + m];
            else if (bias && k1 == K) w1 = bias[m];
        }
        d[i] = pkbf(w0, w1);
    }
    int4v v; v.x = d[0]; v.y = d[1]; v.z = d[2]; v.w = d[3];
    return i4_to_frag(v);
}

// bias vector in C layout (all 32 rows)
DEV vfloat16 bvec32(const float* __restrict__ b, int lane) {
    int h = lane >> 5;
    vfloat16 v;
#pragma unroll
    for (int reg = 0; reg < 16; ++reg)
        v[reg] = b[(reg & 3) + 8 * (reg >> 2) + 4 * h];
    return v;
}
// bias vector, rows 0..15 only (regs 0..7), upper 8 zero
DEV vfloat16 bvec16(const float* __restrict__ b, int lane) {
    int h = lane >> 5;
    vfloat16 v;
#pragma unroll
    for (int reg = 0; reg < 16; ++reg)
        v[reg] = (reg < 8) ? b[(reg & 3) + 8 * (reg >> 2) + 4 * h] : 0.f;
    return v;
}

DEV vfloat16 zero16() {
    vfloat16 z;
#pragma unroll
    for (int i = 0; i < 16; ++i) z[i] = 0.f;
    return z;
}

// B1 frag from pre-packed LDS dwords: x at k=0..3, 1.0 at k=4 (bias slot).
// h-lanes map to k=8..15 where A1 is zero -> no masking needed.
DEV bf16x8 b1_from(int2 d) {
    int4v v;
    v.x = d.x;
    v.y = d.y;
    v.z = 0x00003f80;          // bf16(1.0) at k=4
    v.w = 0;
    return i4_to_frag(v);
}

struct Frags {
    bf16x8 A1, A2lo, A2hi, A3lo, A3hi;
    vfloat16 b2, b3;   // L2/L3 biases as MFMA C-operand inits (L1 bias rides k=4)
};

DEV void load_frags(Frags& F,
                    const float* __restrict__ W1, const float* __restrict__ b1,
                    const float* __restrict__ W2, const float* __restrict__ b2,
                    const float* __restrict__ W3, const float* __restrict__ b3,
                    int lane) {
    F.A1   = make_afrag(W1, b1,      32, 32, 4,  0,  lane);
    F.A2lo = make_afrag(W2, nullptr, 32, 32, 32, 0,  lane);
    F.A2hi = make_afrag(W2, nullptr, 32, 32, 32, 16, lane);
    F.A3lo = make_afrag(W3, nullptr, 16, 16, 32, 0,  lane);
    F.A3hi = make_afrag(W3, nullptr, 16, 16, 32, 16, lane);
    F.b2 = bvec32(b2, lane);
    F.b3 = bvec16(b3, lane);
}

// single chain (epilogue use): L1..L3, returns pre-relu C3 (regs 0..7 valid)
DEV vfloat16 run_mlp3(bf16x8 B1, const Frags& F, bool h) {
    vfloat16 C1 = mfma32(F.A1, B1, zero16());
    bf16x8 Blo = xposeB(C1[0], C1[1], C1[2], C1[3], C1[4], C1[5], C1[6], C1[7], h);
    bf16x8 Bhi = xposeB(C1[8], C1[9], C1[10], C1[11], C1[12], C1[13], C1[14], C1[15], h);
    vfloat16 C2 = mfma32(F.A2lo, Blo, F.b2);
    C2 = mfma32(F.A2hi, Bhi, C2);
    Blo = xposeB(C2[0], C2[1], C2[2], C2[3], C2[4], C2[5], C2[6], C2[7], h);
    Bhi = xposeB(C2[8], C2[9], C2[10], C2[11], C2[12], C2[13], C2[14], C2[15], h);
    vfloat16 C3 = mfma32(F.A3lo, Blo, F.b3);
    C3 = mfma32(F.A3hi, Bhi, C3);
    return C3;
}

// LDS x-stage: pre-packed bf16, [agent][row] int2, agent stride 66 dwords
#define XSTRIDE 66

__global__ __launch_bounds__(256)
__attribute__((amdgpu_waves_per_eu(3, 3)))   // cap scheduler's occupancy target:
// budget ~170 VGPR/wave so MFMA accumulators stay in arch VGPRs (no accvgpr
// shuttling).  min==max prevents the allocator squeezing to 84 VGPR + AGPRs.
void dqn_kernel(const float* __restrict__ x, const int* __restrict__ selp,
                const float* __restrict__ oW1, const float* __restrict__ ob1,
                const float* __restrict__ oW2, const float* __restrict__ ob2,
                const float* __restrict__ oW3, const float* __restrict__ ob3,
                const float* __restrict__ sW1, const float* __restrict__ sb1,
                const float* __restrict__ sW2, const float* __restrict__ sb2,
                const float* __restrict__ sW3, const float* __restrict__ sb3,
                const float* __restrict__ gW1, const float* __restrict__ gb1,
                const float* __restrict__ gW2, const float* __restrict__ gb2,
                float* __restrict__ out)
{
    __shared__ int   lds_xb[32 * XSTRIDE];    // 8.4 KB pre-packed bf16 x
    __shared__ float lds_red[3][8][64];       // 6 KB partial agent-sums

    const int tid  = threadIdx.x;
    const int lane = tid & 63;
    const int wave = tid >> 6;
    const bool h = lane >= 32;
    const int c = lane & 31;
    const int sel = *selp;
    const int base0 = blockIdx.x * 32;        // 32 batch rows per block

    // ---- stage x: coalesced fp32 read -> bf16 pack -> LDS [agent][row] ----
    {
        const float* xblk = x + (size_t)base0 * 128;
#pragma unroll
        for (int k = 0; k < 4; ++k) {
            int f = tid + 256 * k;            // float4 index in 32x32 tile
            int row = f >> 5;
            int ag  = f & 31;
            float4 v = *(const float4*)(xblk + (size_t)f * 4);
            int2 d;
            d.x = pkbf(v.x, v.y);
            d.y = pkbf(v.z, v.w);
            *(int2*)&lds_xb[ag * XSTRIDE + row * 2] = d;
        }
    }

    // "other"-MLP weight fragments (global; latency overlaps staging)
    Frags Fo;
    load_frags(Fo, oW1, ob1, oW2, ob2, oW3, ob3, lane);

    __syncthreads();

    // ---- main loop: 8 agents per wave, TWO chains fully interleaved ----
    float sum[8] = {0.f, 0.f, 0.f, 0.f, 0.f, 0.f, 0.f, 0.f};
    const int a0 = wave * 8;
    const int* xb = &lds_xb[a0 * XSTRIDE + c * 2];

#pragma unroll
    for (int i = 0; i < 8; i += 2) {
        int2 da = *(const int2*)(xb + i * XSTRIDE);
        int2 db = *(const int2*)(xb + (i + 1) * XSTRIDE);

        vfloat16 C1a = mfma32(Fo.A1, b1_from(da), zero16());
        vfloat16 C1b = mfma32(Fo.A1, b1_from(db), zero16());

        bf16x8 Bal = xposeB(C1a[0], C1a[1], C1a[2], C1a[3], C1a[4], C1a[5], C1a[6], C1a[7], h);
        bf16x8 Bbl = xposeB(C1b[0], C1b[1], C1b[2], C1b[3], C1b[4], C1b[5], C1b[6], C1b[7], h);
        bf16x8 Bah = xposeB(C1a[8], C1a[9], C1a[10], C1a[11], C1a[12], C1a[13], C1a[14], C1a[15], h);
        bf16x8 Bbh = xposeB(C1b[8], C1b[9], C1b[10], C1b[11], C1b[12], C1b[13], C1b[14], C1b[15], h);

        vfloat16 C2a = mfma32(Fo.A2lo, Bal, Fo.b2);
        vfloat16 C2b = mfma32(Fo.A2lo, Bbl, Fo.b2);
        C2a = mfma32(Fo.A2hi, Bah, C2a);
        C2b = mfma32(Fo.A2hi, Bbh, C2b);

        Bal = xposeB(C2a[0], C2a[1], C2a[2], C2a[3], C2a[4], C2a[5], C2a[6], C2a[7], h);
        Bbl = xposeB(C2b[0], C2b[1], C2b[2], C2b[3], C2b[4], C2b[5], C2b[6], C2b[7], h);
        Bah = xposeB(C2a[8], C2a[9], C2a[10], C2a[11], C2a[12], C2a[13], C2a[14], C2a[15], h);
        Bbh = xposeB(C2b[8], C2b[9], C2b[10], C2b[11], C2b[12], C2b[13], C2b[14], C2b[15], h);

        vfloat16 C3a = mfma32(Fo.A3lo, Bal, Fo.b3);
        vfloat16 C3b = mfma32(Fo.A3lo, Bbl, Fo.b3);
        C3a = mfma32(Fo.A3hi, Bah, C3a);
        C3b = mfma32(Fo.A3hi, Bbh, C3b);

        if (a0 + i != sel) {
#pragma unroll
            for (int j = 0; j < 8; ++j) sum[j] += fmaxf(C3a[j], 0.f);
        }
        if (a0 + i + 1 != sel) {
#pragma unroll
            for (int j = 0; j < 8; ++j) sum[j] += fmaxf(C3b[j], 0.f);
        }
    }

    // ---- merge partial sums across the 4 waves ----
    if (wave != 0) {
#pragma unroll
        for (int i = 0; i < 8; ++i) lds_red[wave - 1][i][lane] = sum[i];
    }
    __syncthreads();

    if (wave == 0) {
#pragma unroll
        for (int j = 0; j < 3; ++j)
#pragma unroll
            for (int i = 0; i < 8; ++i) sum[i] += lds_red[j][i][lane];

        // selected-agent MLP (packed x from LDS; weights from global/L2)
        Frags Fs;
        load_frags(Fs, sW1, sb1, sW2, sb2, sW3, sb3, lane);
        int2 ds = *(const int2*)&lds_xb[sel * XSTRIDE + c * 2];
        vfloat16 C3s = run_mlp3(b1_from(ds), Fs, h);

        // gate layer 1: concat([sel_out, sum_other]) @ gW1 + gb1, relu
        bf16x8 Ag_lo = make_afrag(gW1, nullptr, 32, 32, 32, 0,  lane);
        bf16x8 Ag_hi = make_afrag(gW1, nullptr, 32, 32, 32, 16, lane);
        vfloat16 gb1v = bvec32(gb1, lane);
        bf16x8 Bg_lo = xposeB(C3s[0], C3s[1], C3s[2], C3s[3],
                              C3s[4], C3s[5], C3s[6], C3s[7], h);   // relu folded
        bf16x8 Bg_hi = xposeB(sum[0], sum[1], sum[2], sum[3],
                              sum[4], sum[5], sum[6], sum[7], h);   // sums >= 0
        vfloat16 G = mfma32(Ag_lo, Bg_lo, gb1v);
        G = mfma32(Ag_hi, Bg_hi, G);
#pragma unroll
        for (int i = 0; i < 16; ++i) G[i] = fmaxf(G[i], 0.f);

        // gate layer 2 (32 -> 2) in fp32 VALU + cross-half reduce
        float q0 = 0.f, q1 = 0.f;
#pragma unroll
        for (int reg = 0; reg < 16; ++reg) {
            int row = (reg & 3) + 8 * (reg >> 2) + (h ? 4 : 0);
            q0 += G[reg] * gW2[row * 2 + 0];
            q1 += G[reg] * gW2[row * 2 + 1];
        }
        q0 += __shfl_xor(q0, 32, 64);
        q1 += __shfl_xor(q1, 32, 64);
        q0 += gb2[0];
        q1 += gb2[1];

        if (!h) {
            // action index MUST come from fp32 x (bf16 rounding of values
            // near 1.0 would flip the (int) cast)
            float f3 = x[(size_t)(base0 + c) * 128 + sel * 4 + 3];
            int act = (int)f3;
            act = act < 0 ? 0 : (act > 1 ? 1 : act);
            out[base0 + c] = act ? q1 : q0;
        }
    }
}

extern "C" void kernel_launch(void* const* d_in, const int* in_sizes, int n_in,
                              void* d_out, int out_size, void* d_ws, size_t ws_size,
                              hipStream_t stream) {
    const float* x   = (const float*)d_in[0];
    const int*   sel = (const int*)d_in[1];
    const float* oW1 = (const float*)d_in[2];
    const float* ob1 = (const float*)d_in[3];
    const float* oW2 = (const float*)d_in[4];
    const float* ob2 = (const float*)d_in[5];
    const float* oW3 = (const float*)d_in[6];
    const float* ob3 = (const float*)d_in[7];
    const float* sW1 = (const float*)d_in[8];
    const float* sb1 = (const float*)d_in[9];
    const float* sW2 = (const float*)d_in[10];
    const float* sb2 = (const float*)d_in[11];
    const float* sW3 = (const float*)d_in[12];
    const float* sb3 = (const float*)d_in[13];
    const float* gW1 = (const float*)d_in[14];
    const float* gb1 = (const float*)d_in[15];
    const float* gW2 = (const float*)d_in[16];
    const float* gb2 = (const float*)d_in[17];
    float* out = (float*)d_out;

    const int B = in_sizes[0] / 128;       // 65536
    const int blocks = B / 32;             // 32 batch rows per block, 8 agents/wave
    dqn_kernel<<<blocks, 256, 0, stream>>>(x, sel,
                                           oW1, ob1, oW2, ob2, oW3, ob3,
                                           sW1, sb1, sW2, sb2, sW3, sb3,
                                           gW1, gb1, gW2, gb2, out);
}